// Round 19
// baseline (1096.743 us; speedup 1.0000x reference)
//
#include <hip/hip_runtime.h>
#include <hip/hip_bf16.h>

#define B_ROWS   524288
#define MEL_BINS 128
#define DIM      64
#define KCODES   128

typedef float v2f __attribute__((ext_vector_type(2)));
struct V2P { v2f lo, hi; };

// packed fp32 FMA across INDEPENDENT k-pairs (R18-validated numerically).
#define PKF(A, C, Z) (A) = __builtin_elementwise_fma((C), (Z), (A))

// ---------------- workspace layout (floats) ----------------
#define WS_WT 0
#define WS_P0 (WS_WT + MEL_BINS*DIM)        // 8192
#define WS_P1 (WS_P0 + DIM*KCODES)          // 16384
#define WS_N0 (WS_P1 + DIM*KCODES)          // 24576
#define WS_N1 (WS_N0 + KCODES)              // 24704
#define WS_T0 (WS_N1 + KCODES)              // 24832
#define WS_T1 (WS_T0 + KCODES*MEL_BINS)     // 41216
#define WS_TOT (WS_T1 + KCODES*MEL_BINS)    // 57600 floats

__device__ __forceinline__ float np_pairwise64_sq(const float* v) {
#pragma clang fp contract(off)
    float r0 = v[0]*v[0], r1 = v[1]*v[1], r2 = v[2]*v[2], r3 = v[3]*v[3];
    float r4 = v[4]*v[4], r5 = v[5]*v[5], r6 = v[6]*v[6], r7 = v[7]*v[7];
#pragma unroll
    for (int i = 8; i < 64; i += 8) {
        r0 += v[i+0]*v[i+0]; r1 += v[i+1]*v[i+1];
        r2 += v[i+2]*v[i+2]; r3 += v[i+3]*v[i+3];
        r4 += v[i+4]*v[i+4]; r5 += v[i+5]*v[i+5];
        r6 += v[i+6]*v[i+6]; r7 += v[i+7]*v[i+7];
    }
    return ((r0 + r1) + (r2 + r3)) + ((r4 + r5) + (r6 + r7));
}

__global__ __launch_bounds__(256) void rvq_precomp(
    const float* __restrict__ W_in, const float* __restrict__ cb0,
    const float* __restrict__ cb1, const float* __restrict__ W_out,
    float* __restrict__ ws)
{
#pragma clang fp contract(off)
    float* WT = ws + WS_WT;
    float* P0 = ws + WS_P0;
    float* P1 = ws + WS_P1;
    float* n0 = ws + WS_N0;
    float* n1 = ws + WS_N1;
    float* T0 = ws + WS_T0;
    float* T1 = ws + WS_T1;

    int tid = blockIdx.x * 256 + threadIdx.x;
    if (tid < 16384) {                       // T0[i][m]
        int i = tid >> 7, m = tid & 127;
        double a = 0.0;
        for (int d = 0; d < DIM; ++d)
            a = fma((double)cb0[i*DIM + d], (double)W_out[m*DIM + d], a);
        T0[tid] = (float)a;
    } else if (tid < 32768) {                // T1[i][m]
        int t = tid - 16384;
        int i = t >> 7, m = t & 127;
        double a = 0.0;
        for (int d = 0; d < DIM; ++d)
            a = fma((double)cb1[i*DIM + d], (double)W_out[m*DIM + d], a);
        T1[t] = (float)a;
    } else if (tid < 40960) {                // WT[j][d] = W_in[d][j]
        int t = tid - 32768;
        int j = t >> 6, d = t & 63;
        WT[t] = W_in[d*MEL_BINS + j];
    } else if (tid < 41216) {                // n0 / n1 (exact np pairwise)
        int t = tid - 40960;
        const float* cb = (t & 128) ? cb1 : cb0;
        float*       nn = (t & 128) ? n1  : n0;
        int k = t & 127;
        nn[k] = np_pairwise64_sq(cb + k*DIM);
    } else if (tid < 49408) {                // P0 panels: P0[c*1024+d*16+t]=cb0[(16c+t)*64+d]
        int e = tid - 41216;
        int c = e >> 10, rem = e & 1023;
        int d = rem >> 4, t = rem & 15;
        P0[e] = cb0[(c*16 + t)*DIM + d];
    } else if (tid < 57600) {                // P1 panels
        int e = tid - 49408;
        int c = e >> 10, rem = e & 1023;
        int d = rem >> 4, t = rem & 15;
        P1[e] = cb1[(c*16 + t)*DIM + d];
    }
}

// 2 rows/thread (rows base+tid and base+256+tid: coalesced). R16 transport
// (16 KB staged LDS, uniform ds_read_b128 broadcasts). z kept SCALAR
// (AGPR-offloadable, R16-proven); z-GEMM runs one row at a time per staged
// half so only 64 accumulators are hot. Dots share each codebook read
// across both rows and pack across k-pairs (R18-validated). PER-VALUE FP
// OP ORDER IS BIT-IDENTICAL to the R3-verified np-f32 emulation:
// z_d ascending-j chain; dot_k single accumulator ascending d; np pairwise
// squares; ascending-k strict < argmin. DO NOT REORDER.
__global__ __launch_bounds__(256) void rvq_main(
    const float* __restrict__ mel,
    const float* __restrict__ b_in,
    const float* __restrict__ cb0,
    const float* __restrict__ cb1,
    const float* __restrict__ b_out,
    const float* __restrict__ ws,
    float* __restrict__ out_mel,
    float* __restrict__ out_idx)
{
#pragma clang fp contract(off)
    const float* __restrict__ n0g = ws + WS_N0;
    const float* __restrict__ n1g = ws + WS_N1;
    const float* __restrict__ T0  = ws + WS_T0;
    const float* __restrict__ T1  = ws + WS_T1;

    __shared__ float slds[4096];             // 16 KB staging buffer
    float4* sw4 = reinterpret_cast<float4*>(slds);
    const float4* sl4 = reinterpret_cast<const float4*>(slds);

    const int tid = threadIdx.x;
    const size_t rA = (size_t)blockIdx.x * 512 + tid;
    const size_t rB = rA + 256;
    const float4* melA = reinterpret_cast<const float4*>(mel + rA * MEL_BINS);
    const float4* melB = reinterpret_cast<const float4*>(mel + rB * MEL_BINS);

    float zA[DIM], zB[DIM];
#pragma unroll
    for (int d = 0; d < DIM; ++d) { zA[d] = 0.f; zB[d] = 0.f; }

    // ======== z-GEMM: two j-halves; per half, row A pass then row B pass ====
    const float4* wt4 = reinterpret_cast<const float4*>(ws + WS_WT);
    for (int h = 0; h < 2; ++h) {
        __syncthreads();
#pragma unroll
        for (int i = 0; i < 4; ++i) sw4[i*256 + tid] = wt4[h*1024 + i*256 + tid];
        __syncthreads();

        for (int jc = 0; jc < 16; ++jc) {    // row A: ascending j in this half
            float4 m4 = melA[h*16 + jc];
#pragma unroll
            for (int seg = 0; seg < 4; ++seg) {
                float mj = (seg == 0) ? m4.x : (seg == 1) ? m4.y : (seg == 2) ? m4.z : m4.w;
                const float4* w4 = sl4 + (jc*4 + seg)*16;
#pragma unroll
                for (int q = 0; q < 16; ++q) {
                    float4 wv = w4[q];
                    zA[4*q + 0] = fmaf(wv.x, mj, zA[4*q + 0]);
                    zA[4*q + 1] = fmaf(wv.y, mj, zA[4*q + 1]);
                    zA[4*q + 2] = fmaf(wv.z, mj, zA[4*q + 2]);
                    zA[4*q + 3] = fmaf(wv.w, mj, zA[4*q + 3]);
                }
            }
        }
        for (int jc = 0; jc < 16; ++jc) {    // row B: same half
            float4 m4 = melB[h*16 + jc];
#pragma unroll
            for (int seg = 0; seg < 4; ++seg) {
                float mj = (seg == 0) ? m4.x : (seg == 1) ? m4.y : (seg == 2) ? m4.z : m4.w;
                const float4* w4 = sl4 + (jc*4 + seg)*16;
#pragma unroll
                for (int q = 0; q < 16; ++q) {
                    float4 wv = w4[q];
                    zB[4*q + 0] = fmaf(wv.x, mj, zB[4*q + 0]);
                    zB[4*q + 1] = fmaf(wv.y, mj, zB[4*q + 1]);
                    zB[4*q + 2] = fmaf(wv.z, mj, zB[4*q + 2]);
                    zB[4*q + 3] = fmaf(wv.w, mj, zB[4*q + 3]);
                }
            }
        }
    }
#pragma unroll
    for (int d = 0; d < DIM; ++d) { zA[d] = zA[d] + b_in[d]; zB[d] = zB[d] + b_in[d]; }

    // ---- sum_rr per row (np pairwise, frozen) ----
    float srA, srB;
    {
        float s0 = zA[0]*zA[0], s1 = zA[1]*zA[1], s2 = zA[2]*zA[2], s3 = zA[3]*zA[3];
        float s4 = zA[4]*zA[4], s5 = zA[5]*zA[5], s6 = zA[6]*zA[6], s7 = zA[7]*zA[7];
#pragma unroll
        for (int i = 8; i < 64; i += 8) {
            s0 += zA[i+0]*zA[i+0]; s1 += zA[i+1]*zA[i+1];
            s2 += zA[i+2]*zA[i+2]; s3 += zA[i+3]*zA[i+3];
            s4 += zA[i+4]*zA[i+4]; s5 += zA[i+5]*zA[i+5];
            s6 += zA[i+6]*zA[i+6]; s7 += zA[i+7]*zA[i+7];
        }
        srA = ((s0 + s1) + (s2 + s3)) + ((s4 + s5) + (s6 + s7));
    }
    {
        float s0 = zB[0]*zB[0], s1 = zB[1]*zB[1], s2 = zB[2]*zB[2], s3 = zB[3]*zB[3];
        float s4 = zB[4]*zB[4], s5 = zB[5]*zB[5], s6 = zB[6]*zB[6], s7 = zB[7]*zB[7];
#pragma unroll
        for (int i = 8; i < 64; i += 8) {
            s0 += zB[i+0]*zB[i+0]; s1 += zB[i+1]*zB[i+1];
            s2 += zB[i+2]*zB[i+2]; s3 += zB[i+3]*zB[i+3];
            s4 += zB[i+4]*zB[i+4]; s5 += zB[i+5]*zB[i+5];
            s6 += zB[i+6]*zB[i+6]; s7 += zB[i+7]*zB[i+7];
        }
        srB = ((s0 + s1) + (s2 + s3)) + ((s4 + s5) + (s6 + s7));
    }

    // ======== codebook 0: shared reads, k-packed, both rows ========
    const float4* p04 = reinterpret_cast<const float4*>(ws + WS_P0);
    float bestA = 3.4e38f, bestB = 3.4e38f; int i0A = 0, i0B = 0;
    for (int h = 0; h < 2; ++h) {
        __syncthreads();
#pragma unroll
        for (int i = 0; i < 4; ++i) sw4[i*256 + tid] = p04[h*1024 + i*256 + tid];
        __syncthreads();

        for (int q = 0; q < 4; ++q) {
            const float4* pan = sl4 + q*256;
            v2f avA[8], avB[8];
#pragma unroll
            for (int t = 0; t < 8; ++t) { avA[t] = (v2f){0.f,0.f}; avB[t] = (v2f){0.f,0.f}; }
#pragma unroll
            for (int d = 0; d < DIM; ++d) {
                V2P P0 = __builtin_bit_cast(V2P, pan[d*4 + 0]);
                V2P P1 = __builtin_bit_cast(V2P, pan[d*4 + 1]);
                V2P P2 = __builtin_bit_cast(V2P, pan[d*4 + 2]);
                V2P P3 = __builtin_bit_cast(V2P, pan[d*4 + 3]);
                float a = zA[d]; v2f a2 = (v2f){a, a};
                float b = zB[d]; v2f b2 = (v2f){b, b};
                PKF(avA[0], P0.lo, a2); PKF(avA[1], P0.hi, a2);
                PKF(avA[2], P1.lo, a2); PKF(avA[3], P1.hi, a2);
                PKF(avA[4], P2.lo, a2); PKF(avA[5], P2.hi, a2);
                PKF(avA[6], P3.lo, a2); PKF(avA[7], P3.hi, a2);
                PKF(avB[0], P0.lo, b2); PKF(avB[1], P0.hi, b2);
                PKF(avB[2], P1.lo, b2); PKF(avB[3], P1.hi, b2);
                PKF(avB[4], P2.lo, b2); PKF(avB[5], P2.hi, b2);
                PKF(avB[6], P3.lo, b2); PKF(avB[7], P3.hi, b2);
            }
            const int kb = h*64 + q*16;
            const float* nk = n0g + kb;
#pragma unroll
            for (int j = 0; j < 8; ++j) {    // ascending k, strict < (np.argmin)
                float nA0 = nk[2*j + 0], nA1 = nk[2*j + 1];
                float dA0 = (srA - 2.0f*avA[j].x) + nA0;
                float dA1 = (srA - 2.0f*avA[j].y) + nA1;
                float dB0 = (srB - 2.0f*avB[j].x) + nA0;
                float dB1 = (srB - 2.0f*avB[j].y) + nA1;
                if (dA0 < bestA) { bestA = dA0; i0A = kb + 2*j + 0; }
                if (dA1 < bestA) { bestA = dA1; i0A = kb + 2*j + 1; }
                if (dB0 < bestB) { bestB = dB0; i0B = kb + 2*j + 0; }
                if (dB1 < bestB) { bestB = dB1; i0B = kb + 2*j + 1; }
            }
        }
    }

    // ---- residual per row (frozen sub), fresh sum_rr ----
    {
        const float* cc = cb0 + (size_t)i0A * DIM;
#pragma unroll
        for (int d = 0; d < DIM; ++d) zA[d] = zA[d] - cc[d];
    }
    {
        const float* cc = cb0 + (size_t)i0B * DIM;
#pragma unroll
        for (int d = 0; d < DIM; ++d) zB[d] = zB[d] - cc[d];
    }
    {
        float s0 = zA[0]*zA[0], s1 = zA[1]*zA[1], s2 = zA[2]*zA[2], s3 = zA[3]*zA[3];
        float s4 = zA[4]*zA[4], s5 = zA[5]*zA[5], s6 = zA[6]*zA[6], s7 = zA[7]*zA[7];
#pragma unroll
        for (int i = 8; i < 64; i += 8) {
            s0 += zA[i+0]*zA[i+0]; s1 += zA[i+1]*zA[i+1];
            s2 += zA[i+2]*zA[i+2]; s3 += zA[i+3]*zA[i+3];
            s4 += zA[i+4]*zA[i+4]; s5 += zA[i+5]*zA[i+5];
            s6 += zA[i+6]*zA[i+6]; s7 += zA[i+7]*zA[i+7];
        }
        srA = ((s0 + s1) + (s2 + s3)) + ((s4 + s5) + (s6 + s7));
    }
    {
        float s0 = zB[0]*zB[0], s1 = zB[1]*zB[1], s2 = zB[2]*zB[2], s3 = zB[3]*zB[3];
        float s4 = zB[4]*zB[4], s5 = zB[5]*zB[5], s6 = zB[6]*zB[6], s7 = zB[7]*zB[7];
#pragma unroll
        for (int i = 8; i < 64; i += 8) {
            s0 += zB[i+0]*zB[i+0]; s1 += zB[i+1]*zB[i+1];
            s2 += zB[i+2]*zB[i+2]; s3 += zB[i+3]*zB[i+3];
            s4 += zB[i+4]*zB[i+4]; s5 += zB[i+5]*zB[i+5];
            s6 += zB[i+6]*zB[i+6]; s7 += zB[i+7]*zB[i+7];
        }
        srB = ((s0 + s1) + (s2 + s3)) + ((s4 + s5) + (s6 + s7));
    }

    // ======== codebook 1 ========
    const float4* p14 = reinterpret_cast<const float4*>(ws + WS_P1);
    float best1A = 3.4e38f, best1B = 3.4e38f; int i1A = 0, i1B = 0;
    for (int h = 0; h < 2; ++h) {
        __syncthreads();
#pragma unroll
        for (int i = 0; i < 4; ++i) sw4[i*256 + tid] = p14[h*1024 + i*256 + tid];
        __syncthreads();

        for (int q = 0; q < 4; ++q) {
            const float4* pan = sl4 + q*256;
            v2f avA[8], avB[8];
#pragma unroll
            for (int t = 0; t < 8; ++t) { avA[t] = (v2f){0.f,0.f}; avB[t] = (v2f){0.f,0.f}; }
#pragma unroll
            for (int d = 0; d < DIM; ++d) {
                V2P P0 = __builtin_bit_cast(V2P, pan[d*4 + 0]);
                V2P P1 = __builtin_bit_cast(V2P, pan[d*4 + 1]);
                V2P P2 = __builtin_bit_cast(V2P, pan[d*4 + 2]);
                V2P P3 = __builtin_bit_cast(V2P, pan[d*4 + 3]);
                float a = zA[d]; v2f a2 = (v2f){a, a};
                float b = zB[d]; v2f b2 = (v2f){b, b};
                PKF(avA[0], P0.lo, a2); PKF(avA[1], P0.hi, a2);
                PKF(avA[2], P1.lo, a2); PKF(avA[3], P1.hi, a2);
                PKF(avA[4], P2.lo, a2); PKF(avA[5], P2.hi, a2);
                PKF(avA[6], P3.lo, a2); PKF(avA[7], P3.hi, a2);
                PKF(avB[0], P0.lo, b2); PKF(avB[1], P0.hi, b2);
                PKF(avB[2], P1.lo, b2); PKF(avB[3], P1.hi, b2);
                PKF(avB[4], P2.lo, b2); PKF(avB[5], P2.hi, b2);
                PKF(avB[6], P3.lo, b2); PKF(avB[7], P3.hi, b2);
            }
            const int kb = h*64 + q*16;
            const float* nk = n1g + kb;
#pragma unroll
            for (int j = 0; j < 8; ++j) {
                float nA0 = nk[2*j + 0], nA1 = nk[2*j + 1];
                float dA0 = (srA - 2.0f*avA[j].x) + nA0;
                float dA1 = (srA - 2.0f*avA[j].y) + nA1;
                float dB0 = (srB - 2.0f*avB[j].x) + nA0;
                float dB1 = (srB - 2.0f*avB[j].y) + nA1;
                if (dA0 < best1A) { best1A = dA0; i1A = kb + 2*j + 0; }
                if (dA1 < best1A) { best1A = dA1; i1A = kb + 2*j + 1; }
                if (dB0 < best1B) { best1B = dB0; i1B = kb + 2*j + 0; }
                if (dB1 < best1B) { best1B = dB1; i1B = kb + 2*j + 1; }
            }
        }
    }

    // ---- decode both rows: out = T0[i0] + T1[i1] + b_out ----
    {
        const float4* t0r = reinterpret_cast<const float4*>(T0 + (size_t)i0A * MEL_BINS);
        const float4* t1r = reinterpret_cast<const float4*>(T1 + (size_t)i1A * MEL_BINS);
        float4* outr = reinterpret_cast<float4*>(out_mel + rA * MEL_BINS);
#pragma unroll 4
        for (int q = 0; q < MEL_BINS / 4; ++q) {
            float4 a = t0r[q], cc = t1r[q];
            float4 o;
            o.x = a.x + cc.x + b_out[4*q + 0];
            o.y = a.y + cc.y + b_out[4*q + 1];
            o.z = a.z + cc.z + b_out[4*q + 2];
            o.w = a.w + cc.w + b_out[4*q + 3];
            outr[q] = o;
        }
    }
    {
        const float4* t0r = reinterpret_cast<const float4*>(T0 + (size_t)i0B * MEL_BINS);
        const float4* t1r = reinterpret_cast<const float4*>(T1 + (size_t)i1B * MEL_BINS);
        float4* outr = reinterpret_cast<float4*>(out_mel + rB * MEL_BINS);
#pragma unroll 4
        for (int q = 0; q < MEL_BINS / 4; ++q) {
            float4 a = t0r[q], cc = t1r[q];
            float4 o;
            o.x = a.x + cc.x + b_out[4*q + 0];
            o.y = a.y + cc.y + b_out[4*q + 1];
            o.z = a.z + cc.z + b_out[4*q + 2];
            o.w = a.w + cc.w + b_out[4*q + 3];
            outr[q] = o;
        }
    }

    out_idx[2*rA + 0] = (float)i0A;
    out_idx[2*rA + 1] = (float)i1A;
    out_idx[2*rB + 0] = (float)i0B;
    out_idx[2*rB + 1] = (float)i1B;
}

extern "C" void kernel_launch(void* const* d_in, const int* in_sizes, int n_in,
                              void* d_out, int out_size, void* d_ws, size_t ws_size,
                              hipStream_t stream)
{
    const float* mel   = (const float*)d_in[0];
    const float* W_in  = (const float*)d_in[1];
    const float* b_in  = (const float*)d_in[2];
    const float* cb0   = (const float*)d_in[3];
    const float* cb1   = (const float*)d_in[4];
    const float* W_out = (const float*)d_in[5];
    const float* b_out = (const float*)d_in[6];

    float* ws      = (float*)d_ws;                 // 230400 bytes used
    float* out_mel = (float*)d_out;
    float* out_idx = (float*)d_out + (size_t)B_ROWS * MEL_BINS;

    rvq_precomp<<<(WS_TOT + 255) / 256, 256, 0, stream>>>(W_in, cb0, cb1, W_out, ws);
    rvq_main<<<B_ROWS / 512, 256, 0, stream>>>(mel, b_in, cb0, cb1, b_out, ws,
                                               out_mel, out_idx);
}

// Round 20
// 865.816 us; speedup vs baseline: 1.2667x; 1.2667x over previous
//
#include <hip/hip_runtime.h>
#include <hip/hip_bf16.h>

#define B_ROWS   524288
#define MEL_BINS 128
#define DIM      64
#define KCODES   128

// ---------------- workspace layout (floats) ----------------
// WT [128*64]  : W_in^T, WT[j*64+d] = W_in[d*128+j]   (read via s_load)
// P0 [8*1024]  : cb0 16-k panels, P0[c*1024 + d*16 + t] = cb0[(c*16+t)*64 + d]
// P1 [8*1024]  : cb1 panels
// n0,n1 [128]  : np pairwise ||c_k||^2
// T0,T1 [128*128] : cb @ W_out^T
#define WS_WT 0
#define WS_P0 (WS_WT + MEL_BINS*DIM)        // 8192
#define WS_P1 (WS_P0 + DIM*KCODES)          // 16384
#define WS_N0 (WS_P1 + DIM*KCODES)          // 24576
#define WS_N1 (WS_N0 + KCODES)              // 24704
#define WS_T0 (WS_N1 + KCODES)              // 24832
#define WS_T1 (WS_T0 + KCODES*MEL_BINS)     // 41216
#define WS_TOT (WS_T1 + KCODES*MEL_BINS)    // 57600 floats

__device__ __forceinline__ float np_pairwise64_sq(const float* v) {
#pragma clang fp contract(off)
    float r0 = v[0]*v[0], r1 = v[1]*v[1], r2 = v[2]*v[2], r3 = v[3]*v[3];
    float r4 = v[4]*v[4], r5 = v[5]*v[5], r6 = v[6]*v[6], r7 = v[7]*v[7];
#pragma unroll
    for (int i = 8; i < 64; i += 8) {
        r0 += v[i+0]*v[i+0]; r1 += v[i+1]*v[i+1];
        r2 += v[i+2]*v[i+2]; r3 += v[i+3]*v[i+3];
        r4 += v[i+4]*v[i+4]; r5 += v[i+5]*v[i+5];
        r6 += v[i+6]*v[i+6]; r7 += v[i+7]*v[i+7];
    }
    return ((r0 + r1) + (r2 + r3)) + ((r4 + r5) + (r6 + r7));
}

__global__ __launch_bounds__(256) void rvq_precomp(
    const float* __restrict__ W_in, const float* __restrict__ cb0,
    const float* __restrict__ cb1, const float* __restrict__ W_out,
    float* __restrict__ ws)
{
#pragma clang fp contract(off)
    float* WT = ws + WS_WT;
    float* P0 = ws + WS_P0;
    float* P1 = ws + WS_P1;
    float* n0 = ws + WS_N0;
    float* n1 = ws + WS_N1;
    float* T0 = ws + WS_T0;
    float* T1 = ws + WS_T1;

    int tid = blockIdx.x * 256 + threadIdx.x;
    if (tid < 16384) {                       // T0[i][m] (mel path: loose threshold)
        int i = tid >> 7, m = tid & 127;
        double a = 0.0;
        for (int d = 0; d < DIM; ++d)
            a = fma((double)cb0[i*DIM + d], (double)W_out[m*DIM + d], a);
        T0[tid] = (float)a;
    } else if (tid < 32768) {                // T1[i][m]
        int t = tid - 16384;
        int i = t >> 7, m = t & 127;
        double a = 0.0;
        for (int d = 0; d < DIM; ++d)
            a = fma((double)cb1[i*DIM + d], (double)W_out[m*DIM + d], a);
        T1[t] = (float)a;
    } else if (tid < 40960) {                // WT[j][d] = W_in[d][j]
        int t = tid - 32768;
        int j = t >> 6, d = t & 63;
        WT[t] = W_in[d*MEL_BINS + j];
    } else if (tid < 41216) {                // n0 / n1 (exact np pairwise)
        int t = tid - 40960;
        const float* cb = (t & 128) ? cb1 : cb0;
        float*       nn = (t & 128) ? n1  : n0;
        int k = t & 127;
        nn[k] = np_pairwise64_sq(cb + k*DIM);
    } else if (tid < 49408) {                // P0 panels
        int e = tid - 41216;
        int c = e >> 10, rem = e & 1023;
        int d = rem >> 4, t = rem & 15;
        P0[e] = cb0[(c*16 + t)*DIM + d];
    } else if (tid < 57600) {                // P1 panels
        int e = tid - 49408;
        int c = e >> 10, rem = e & 1023;
        int d = rem >> 4, t = rem & 15;
        P1[e] = cb1[(c*16 + t)*DIM + d];
    }
}

// 1 row/thread. z-GEMM: d-blocked (16 hot arch-VGPR accumulators, R10-verified
// order) with WT via wave-uniform s_load (scalar pipe, K$) and mel re-read
// (L1-hot) -> no AGPR shuffle, no GEMM LDS traffic. Dots: R16-verbatim
// (16 KB LDS codebook panels, uniform ds_read_b128 broadcasts, acc[16] ILP).
// PER-VALUE FP OP ORDER IS BIT-IDENTICAL to the R3-verified np-f32 emulation:
// z_d ascending-j chain; dot_k single accumulator ascending d; np 8-acc
// pairwise squares; ascending-k strict < argmin. DO NOT REORDER.
__global__ __launch_bounds__(256) void rvq_main(
    const float* __restrict__ mel,
    const float* __restrict__ b_in,
    const float* __restrict__ cb0,
    const float* __restrict__ cb1,
    const float* __restrict__ b_out,
    const float* __restrict__ ws,
    float* __restrict__ out_mel,
    float* __restrict__ out_idx)
{
#pragma clang fp contract(off)
    const float* __restrict__ WTg = ws + WS_WT;
    const float* __restrict__ n0g = ws + WS_N0;
    const float* __restrict__ n1g = ws + WS_N1;
    const float* __restrict__ T0  = ws + WS_T0;
    const float* __restrict__ T1  = ws + WS_T1;

    __shared__ float slds[4096];             // 16 KB codebook-panel buffer
    float4* sw4 = reinterpret_cast<float4*>(slds);
    const float4* sl4 = reinterpret_cast<const float4*>(slds);

    const int tid = threadIdx.x;
    const int b = blockIdx.x * 256 + tid;
    const float4* melr = reinterpret_cast<const float4*>(mel + (size_t)b * MEL_BINS);

    float z[DIM];                            // parked per-block (AGPR-friendly)
    float r8[8];                             // np pairwise square accumulators
#pragma unroll
    for (int t = 0; t < 8; ++t) r8[t] = 0.f;

    // ======== z-GEMM: 4 d-blocks x 16 hot accumulators, WT via s_load ========
#pragma unroll
    for (int db = 0; db < 4; ++db) {
        float zz[16];
#pragma unroll
        for (int t = 0; t < 16; ++t) zz[t] = 0.f;

        for (int jc = 0; jc < 32; ++jc) {
            float4 m4 = melr[jc];                         // L1-hot on re-reads
            const float* w = WTg + jc * 4 * DIM + db * 16; // wave-uniform -> s_load
#pragma unroll
            for (int t = 0; t < 16; ++t) zz[t] = fmaf(w[t],         m4.x, zz[t]);
#pragma unroll
            for (int t = 0; t < 16; ++t) zz[t] = fmaf(w[DIM + t],   m4.y, zz[t]);
#pragma unroll
            for (int t = 0; t < 16; ++t) zz[t] = fmaf(w[2*DIM + t], m4.z, zz[t]);
#pragma unroll
            for (int t = 0; t < 16; ++t) zz[t] = fmaf(w[3*DIM + t], m4.w, zz[t]);
        }
#pragma unroll
        for (int t = 0; t < 16; ++t) {
            float v = zz[t] + b_in[db*16 + t];   // separate rounded bias add
            z[db*16 + t] = v;                    // park (static index)
            r8[t & 7] += v * v;                  // ascending d per accumulator ✓
        }
        asm volatile("" ::: "memory");           // no mel-load CSE across blocks
    }
    float sum_rr = ((r8[0] + r8[1]) + (r8[2] + r8[3])) + ((r8[4] + r8[5]) + (r8[6] + r8[7]));

    // ======== codebook 0: k-halves staged in LDS, chunks of 16 k, acc[16] ====
    const float4* p04 = reinterpret_cast<const float4*>(ws + WS_P0);
    float best0 = 3.4e38f; int i0 = 0;
    for (int h = 0; h < 2; ++h) {
        __syncthreads();
#pragma unroll
        for (int i = 0; i < 4; ++i) sw4[i*256 + tid] = p04[h*1024 + i*256 + tid];
        __syncthreads();

        for (int q = 0; q < 4; ++q) {        // chunk: k = h*64 + q*16 + t
            const float4* pan = sl4 + q*256;
            float acc[16];
#pragma unroll
            for (int t = 0; t < 16; ++t) acc[t] = 0.f;
#pragma unroll
            for (int d = 0; d < DIM; ++d) {  // FULL unroll: z[d]/acc[t] static
                float4 p0 = pan[d*4 + 0];
                float4 p1 = pan[d*4 + 1];
                float4 p2 = pan[d*4 + 2];
                float4 p3 = pan[d*4 + 3];
                float zd = z[d];
                acc[ 0] = fmaf(p0.x, zd, acc[ 0]);
                acc[ 1] = fmaf(p0.y, zd, acc[ 1]);
                acc[ 2] = fmaf(p0.z, zd, acc[ 2]);
                acc[ 3] = fmaf(p0.w, zd, acc[ 3]);
                acc[ 4] = fmaf(p1.x, zd, acc[ 4]);
                acc[ 5] = fmaf(p1.y, zd, acc[ 5]);
                acc[ 6] = fmaf(p1.z, zd, acc[ 6]);
                acc[ 7] = fmaf(p1.w, zd, acc[ 7]);
                acc[ 8] = fmaf(p2.x, zd, acc[ 8]);
                acc[ 9] = fmaf(p2.y, zd, acc[ 9]);
                acc[10] = fmaf(p2.z, zd, acc[10]);
                acc[11] = fmaf(p2.w, zd, acc[11]);
                acc[12] = fmaf(p3.x, zd, acc[12]);
                acc[13] = fmaf(p3.y, zd, acc[13]);
                acc[14] = fmaf(p3.z, zd, acc[14]);
                acc[15] = fmaf(p3.w, zd, acc[15]);
            }
            const int kb = h*64 + q*16;
            const float* nk = n0g + kb;
#pragma unroll
            for (int t = 0; t < 16; ++t) {   // ascending k, strict < (np.argmin)
                float dist = (sum_rr - 2.0f*acc[t]) + nk[t];
                if (dist < best0) { best0 = dist; i0 = kb + t; }
            }
        }
    }

    // ---- residual = z - cb0[i0] : per-lane global gather (L2-hot), frozen sub
    {
        const float* cc = cb0 + (size_t)i0 * DIM;
#pragma unroll
        for (int d = 0; d < DIM; ++d) z[d] = z[d] - cc[d];
    }

    // ---- sum_rr' (np pairwise, frozen) ----
#pragma unroll
    for (int t = 0; t < 8; ++t) r8[t] = 0.f;
#pragma unroll
    for (int i = 0; i < 64; i += 8) {
#pragma unroll
        for (int t = 0; t < 8; ++t) r8[t] += z[i + t] * z[i + t];
    }
    sum_rr = ((r8[0] + r8[1]) + (r8[2] + r8[3])) + ((r8[4] + r8[5]) + (r8[6] + r8[7]));

    // ======== codebook 1 ========
    const float4* p14 = reinterpret_cast<const float4*>(ws + WS_P1);
    float best1 = 3.4e38f; int i1 = 0;
    for (int h = 0; h < 2; ++h) {
        __syncthreads();
#pragma unroll
        for (int i = 0; i < 4; ++i) sw4[i*256 + tid] = p14[h*1024 + i*256 + tid];
        __syncthreads();

        for (int q = 0; q < 4; ++q) {
            const float4* pan = sl4 + q*256;
            float acc[16];
#pragma unroll
            for (int t = 0; t < 16; ++t) acc[t] = 0.f;
#pragma unroll
            for (int d = 0; d < DIM; ++d) {
                float4 p0 = pan[d*4 + 0];
                float4 p1 = pan[d*4 + 1];
                float4 p2 = pan[d*4 + 2];
                float4 p3 = pan[d*4 + 3];
                float zd = z[d];
                acc[ 0] = fmaf(p0.x, zd, acc[ 0]);
                acc[ 1] = fmaf(p0.y, zd, acc[ 1]);
                acc[ 2] = fmaf(p0.z, zd, acc[ 2]);
                acc[ 3] = fmaf(p0.w, zd, acc[ 3]);
                acc[ 4] = fmaf(p1.x, zd, acc[ 4]);
                acc[ 5] = fmaf(p1.y, zd, acc[ 5]);
                acc[ 6] = fmaf(p1.z, zd, acc[ 6]);
                acc[ 7] = fmaf(p1.w, zd, acc[ 7]);
                acc[ 8] = fmaf(p2.x, zd, acc[ 8]);
                acc[ 9] = fmaf(p2.y, zd, acc[ 9]);
                acc[10] = fmaf(p2.z, zd, acc[10]);
                acc[11] = fmaf(p2.w, zd, acc[11]);
                acc[12] = fmaf(p3.x, zd, acc[12]);
                acc[13] = fmaf(p3.y, zd, acc[13]);
                acc[14] = fmaf(p3.z, zd, acc[14]);
                acc[15] = fmaf(p3.w, zd, acc[15]);
            }
            const int kb = h*64 + q*16;
            const float* nk = n1g + kb;
#pragma unroll
            for (int t = 0; t < 16; ++t) {
                float dist = (sum_rr - 2.0f*acc[t]) + nk[t];
                if (dist < best1) { best1 = dist; i1 = kb + t; }
            }
        }
    }

    // ---- decode: out = T0[i0] + T1[i1] + b_out ----
    const float4* t0r = reinterpret_cast<const float4*>(T0 + (size_t)i0 * MEL_BINS);
    const float4* t1r = reinterpret_cast<const float4*>(T1 + (size_t)i1 * MEL_BINS);
    float4* outr = reinterpret_cast<float4*>(out_mel + (size_t)b * MEL_BINS);
#pragma unroll 4
    for (int q = 0; q < MEL_BINS / 4; ++q) {
        float4 a = t0r[q], cc = t1r[q];
        float4 o;
        o.x = a.x + cc.x + b_out[4*q + 0];
        o.y = a.y + cc.y + b_out[4*q + 1];
        o.z = a.z + cc.z + b_out[4*q + 2];
        o.w = a.w + cc.w + b_out[4*q + 3];
        outr[q] = o;
    }

    out_idx[2*(size_t)b + 0] = (float)i0;
    out_idx[2*(size_t)b + 1] = (float)i1;
}

extern "C" void kernel_launch(void* const* d_in, const int* in_sizes, int n_in,
                              void* d_out, int out_size, void* d_ws, size_t ws_size,
                              hipStream_t stream)
{
    const float* mel   = (const float*)d_in[0];
    const float* W_in  = (const float*)d_in[1];
    const float* b_in  = (const float*)d_in[2];
    const float* cb0   = (const float*)d_in[3];
    const float* cb1   = (const float*)d_in[4];
    const float* W_out = (const float*)d_in[5];
    const float* b_out = (const float*)d_in[6];

    float* ws      = (float*)d_ws;                 // 230400 bytes used
    float* out_mel = (float*)d_out;
    float* out_idx = (float*)d_out + (size_t)B_ROWS * MEL_BINS;

    rvq_precomp<<<(WS_TOT + 255) / 256, 256, 0, stream>>>(W_in, cb0, cb1, W_out, ws);
    rvq_main<<<B_ROWS / 256, 256, 0, stream>>>(mel, b_in, cb0, cb1, b_out, ws,
                                               out_mel, out_idx);
}

// Round 21
// 484.974 us; speedup vs baseline: 2.2614x; 1.7853x over previous
//
#include <hip/hip_runtime.h>
#include <hip/hip_bf16.h>

#define B_ROWS   524288
#define MEL_BINS 128
#define DIM      64
#define KCODES   128

// ---------------- workspace layout (floats) ----------------
// WT  [8192]  : W_in^T, WT[j*64+d] = W_in[d*128+j]
// PL0 [4096]  : cb0 low-k panels,  PL0[c*512 + d*8 + t] = cb0[(16c+t)*64+d],   t<8
// PS0 [4096]  : cb0 high-k panels, PS0[c*512 + d*8 + u] = cb0[(16c+8+u)*64+d], u<8
// PL1 [4096], PS1 [4096] : same for cb1
// n0,n1 [128] : np pairwise ||c_k||^2
// T0,T1 [16384] : cb @ W_out^T
#define WS_WT  0
#define WS_PL0 (WS_WT + 8192)               // 8192
#define WS_PS0 (WS_PL0 + 4096)              // 12288
#define WS_PL1 (WS_PS0 + 4096)              // 16384
#define WS_PS1 (WS_PL1 + 4096)              // 20480
#define WS_N0  (WS_PS1 + 4096)              // 24576
#define WS_N1  (WS_N0 + KCODES)             // 24704
#define WS_T0  (WS_N1 + KCODES)             // 24832
#define WS_T1  (WS_T0 + KCODES*MEL_BINS)    // 41216
#define WS_TOT (WS_T1 + KCODES*MEL_BINS)    // 57600 floats

__device__ __forceinline__ float np_pairwise64_sq(const float* v) {
#pragma clang fp contract(off)
    float r0 = v[0]*v[0], r1 = v[1]*v[1], r2 = v[2]*v[2], r3 = v[3]*v[3];
    float r4 = v[4]*v[4], r5 = v[5]*v[5], r6 = v[6]*v[6], r7 = v[7]*v[7];
#pragma unroll
    for (int i = 8; i < 64; i += 8) {
        r0 += v[i+0]*v[i+0]; r1 += v[i+1]*v[i+1];
        r2 += v[i+2]*v[i+2]; r3 += v[i+3]*v[i+3];
        r4 += v[i+4]*v[i+4]; r5 += v[i+5]*v[i+5];
        r6 += v[i+6]*v[i+6]; r7 += v[i+7]*v[i+7];
    }
    return ((r0 + r1) + (r2 + r3)) + ((r4 + r5) + (r6 + r7));
}

__global__ __launch_bounds__(256) void rvq_precomp(
    const float* __restrict__ W_in, const float* __restrict__ cb0,
    const float* __restrict__ cb1, const float* __restrict__ W_out,
    float* __restrict__ ws)
{
#pragma clang fp contract(off)
    float* WT  = ws + WS_WT;
    float* PL0 = ws + WS_PL0;
    float* PS0 = ws + WS_PS0;
    float* PL1 = ws + WS_PL1;
    float* PS1 = ws + WS_PS1;
    float* n0  = ws + WS_N0;
    float* n1  = ws + WS_N1;
    float* T0  = ws + WS_T0;
    float* T1  = ws + WS_T1;

    int tid = blockIdx.x * 256 + threadIdx.x;
    if (tid < 16384) {                       // T0[i][m] (mel path: loose threshold)
        int i = tid >> 7, m = tid & 127;
        double a = 0.0;
        for (int d = 0; d < DIM; ++d)
            a = fma((double)cb0[i*DIM + d], (double)W_out[m*DIM + d], a);
        T0[tid] = (float)a;
    } else if (tid < 32768) {                // T1[i][m]
        int t = tid - 16384;
        int i = t >> 7, m = t & 127;
        double a = 0.0;
        for (int d = 0; d < DIM; ++d)
            a = fma((double)cb1[i*DIM + d], (double)W_out[m*DIM + d], a);
        T1[t] = (float)a;
    } else if (tid < 40960) {                // WT[j][d] = W_in[d][j]
        int t = tid - 32768;
        int j = t >> 6, d = t & 63;
        WT[t] = W_in[d*MEL_BINS + j];
    } else if (tid < 41216) {                // n0 / n1 (exact np pairwise)
        int t = tid - 40960;
        const float* cb = (t & 128) ? cb1 : cb0;
        float*       nn = (t & 128) ? n1  : n0;
        int k = t & 127;
        nn[k] = np_pairwise64_sq(cb + k*DIM);
    } else if (tid < 49408) {                // PL0 / PS0
        int e = tid - 41216;                 // 0..8191
        int half = e >> 12;                  // 0: PL0, 1: PS0
        int x = e & 4095;
        int c = x >> 9, rem = x & 511;
        int d = rem >> 3, t = rem & 7;
        if (half == 0) PL0[x] = cb0[(16*c + t)*DIM + d];
        else           PS0[x] = cb0[(16*c + 8 + t)*DIM + d];
    } else if (tid < 57600) {                // PL1 / PS1
        int e = tid - 49408;
        int half = e >> 12;
        int x = e & 4095;
        int c = x >> 9, rem = x & 511;
        int d = rem >> 3, t = rem & 7;
        if (half == 0) PL1[x] = cb1[(16*c + t)*DIM + d];
        else           PS1[x] = cb1[(16*c + 8 + t)*DIM + d];
    }
}

// 1 row/thread. R16 base; dot transport SPLIT across pipes: k 0-7 of each
// chunk from LDS (PL staged once per codebook, uniform ds_read_b128), k 8-15
// from wave-uniform s_load_dwordx8 (SMEM pipe, SGPR operands). Halves the
// dot-phase LDS instruction count. PER-VALUE FP OP ORDER IS BIT-IDENTICAL
// to the R3-verified np-f32 emulation: z_d ascending-j chain; dot_k single
// accumulator ascending d; np 8-acc pairwise squares; ascending-k strict <
// argmin. DO NOT REORDER.
__global__ __launch_bounds__(256) void rvq_main(
    const float* __restrict__ mel,
    const float* __restrict__ b_in,
    const float* __restrict__ cb0,
    const float* __restrict__ cb1,
    const float* __restrict__ b_out,
    const float* __restrict__ ws,
    float* __restrict__ out_mel,
    float* __restrict__ out_idx)
{
#pragma clang fp contract(off)
    const float* __restrict__ ps0g = ws + WS_PS0;
    const float* __restrict__ ps1g = ws + WS_PS1;
    const float* __restrict__ n0g  = ws + WS_N0;
    const float* __restrict__ n1g  = ws + WS_N1;
    const float* __restrict__ T0   = ws + WS_T0;
    const float* __restrict__ T1   = ws + WS_T1;

    __shared__ float slds[4096];             // 16 KB: WT halves, then PL tables
    float4* sw4 = reinterpret_cast<float4*>(slds);
    const float4* sl4 = reinterpret_cast<const float4*>(slds);

    const int tid = threadIdx.x;
    const int b = blockIdx.x * 256 + tid;
    const float4* melr = reinterpret_cast<const float4*>(mel + (size_t)b * MEL_BINS);

    float z[DIM];
#pragma unroll
    for (int d = 0; d < DIM; ++d) z[d] = 0.f;

    // ======== z-GEMM in two j-halves (R16 verbatim: mel read once) ========
    const float4* wt4 = reinterpret_cast<const float4*>(ws + WS_WT);
    for (int h = 0; h < 2; ++h) {
        __syncthreads();
#pragma unroll
        for (int i = 0; i < 4; ++i) sw4[i*256 + tid] = wt4[h*1024 + i*256 + tid];
        __syncthreads();

        for (int jc = 0; jc < 16; ++jc) {    // global j = (h*16+jc)*4 + seg, ascending
            float4 m4 = melr[h*16 + jc];
#pragma unroll
            for (int seg = 0; seg < 4; ++seg) {
                float mj = (seg == 0) ? m4.x : (seg == 1) ? m4.y : (seg == 2) ? m4.z : m4.w;
                const float4* w4 = sl4 + (jc*4 + seg)*16;   // uniform -> broadcast
#pragma unroll
                for (int q = 0; q < 16; ++q) {
                    float4 wv = w4[q];
                    z[4*q + 0] = fmaf(wv.x, mj, z[4*q + 0]);
                    z[4*q + 1] = fmaf(wv.y, mj, z[4*q + 1]);
                    z[4*q + 2] = fmaf(wv.z, mj, z[4*q + 2]);
                    z[4*q + 3] = fmaf(wv.w, mj, z[4*q + 3]);
                }
            }
        }
    }
#pragma unroll
    for (int d = 0; d < DIM; ++d) z[d] = z[d] + b_in[d];

    // ---- sum_rr (np pairwise, frozen) ----
    float s0 = z[0]*z[0], s1 = z[1]*z[1], s2 = z[2]*z[2], s3 = z[3]*z[3];
    float s4 = z[4]*z[4], s5 = z[5]*z[5], s6 = z[6]*z[6], s7 = z[7]*z[7];
#pragma unroll
    for (int i = 8; i < 64; i += 8) {
        s0 += z[i+0]*z[i+0]; s1 += z[i+1]*z[i+1];
        s2 += z[i+2]*z[i+2]; s3 += z[i+3]*z[i+3];
        s4 += z[i+4]*z[i+4]; s5 += z[i+5]*z[i+5];
        s6 += z[i+6]*z[i+6]; s7 += z[i+7]*z[i+7];
    }
    float sum_rr = ((s0 + s1) + (s2 + s3)) + ((s4 + s5) + (s6 + s7));

    // ======== codebook 0: PL staged once (16 KB), PS via s_load ========
    const float4* pl04 = reinterpret_cast<const float4*>(ws + WS_PL0);
    float best0 = 3.4e38f; int i0 = 0;
    __syncthreads();
#pragma unroll
    for (int i = 0; i < 4; ++i) sw4[i*256 + tid] = pl04[i*256 + tid];
    __syncthreads();

    for (int c = 0; c < 8; ++c) {            // chunk: k = c*16 + t
        const float4* pan  = sl4 + c*128;    // 512 floats (k 0-7 per d)
        const float* srow  = ps0g + c*512;   // uniform -> s_load_dwordx8 per d
        float acc[16];
#pragma unroll
        for (int t = 0; t < 16; ++t) acc[t] = 0.f;
#pragma unroll
        for (int d = 0; d < DIM; ++d) {      // each k: single acc, ascending d ✓
            float4 p0 = pan[d*2 + 0];
            float4 p1 = pan[d*2 + 1];
            const float* sr = srow + d*8;
            float zd = z[d];
            acc[ 0] = fmaf(p0.x, zd, acc[ 0]);
            acc[ 1] = fmaf(p0.y, zd, acc[ 1]);
            acc[ 2] = fmaf(p0.z, zd, acc[ 2]);
            acc[ 3] = fmaf(p0.w, zd, acc[ 3]);
            acc[ 4] = fmaf(p1.x, zd, acc[ 4]);
            acc[ 5] = fmaf(p1.y, zd, acc[ 5]);
            acc[ 6] = fmaf(p1.z, zd, acc[ 6]);
            acc[ 7] = fmaf(p1.w, zd, acc[ 7]);
            acc[ 8] = fmaf(sr[0], zd, acc[ 8]);
            acc[ 9] = fmaf(sr[1], zd, acc[ 9]);
            acc[10] = fmaf(sr[2], zd, acc[10]);
            acc[11] = fmaf(sr[3], zd, acc[11]);
            acc[12] = fmaf(sr[4], zd, acc[12]);
            acc[13] = fmaf(sr[5], zd, acc[13]);
            acc[14] = fmaf(sr[6], zd, acc[14]);
            acc[15] = fmaf(sr[7], zd, acc[15]);
        }
        const int kb = c*16;
        const float* nk = n0g + kb;
#pragma unroll
        for (int t = 0; t < 16; ++t) {       // ascending k, strict < (np.argmin)
            float dist = (sum_rr - 2.0f*acc[t]) + nk[t];
            if (dist < best0) { best0 = dist; i0 = kb + t; }
        }
    }

    // ---- residual = z - cb0[i0] : per-lane global gather (L2-hot), frozen sub
    {
        const float* cc = cb0 + (size_t)i0 * DIM;
#pragma unroll
        for (int d = 0; d < DIM; ++d) z[d] = z[d] - cc[d];
    }

    // ---- sum_rr' (np pairwise, frozen) ----
    s0 = z[0]*z[0]; s1 = z[1]*z[1]; s2 = z[2]*z[2]; s3 = z[3]*z[3];
    s4 = z[4]*z[4]; s5 = z[5]*z[5]; s6 = z[6]*z[6]; s7 = z[7]*z[7];
#pragma unroll
    for (int i = 8; i < 64; i += 8) {
        s0 += z[i+0]*z[i+0]; s1 += z[i+1]*z[i+1];
        s2 += z[i+2]*z[i+2]; s3 += z[i+3]*z[i+3];
        s4 += z[i+4]*z[i+4]; s5 += z[i+5]*z[i+5];
        s6 += z[i+6]*z[i+6]; s7 += z[i+7]*z[i+7];
    }
    sum_rr = ((s0 + s1) + (s2 + s3)) + ((s4 + s5) + (s6 + s7));

    // ======== codebook 1 ========
    const float4* pl14 = reinterpret_cast<const float4*>(ws + WS_PL1);
    float best1 = 3.4e38f; int i1 = 0;
    __syncthreads();
#pragma unroll
    for (int i = 0; i < 4; ++i) sw4[i*256 + tid] = pl14[i*256 + tid];
    __syncthreads();

    for (int c = 0; c < 8; ++c) {
        const float4* pan  = sl4 + c*128;
        const float* srow  = ps1g + c*512;
        float acc[16];
#pragma unroll
        for (int t = 0; t < 16; ++t) acc[t] = 0.f;
#pragma unroll
        for (int d = 0; d < DIM; ++d) {
            float4 p0 = pan[d*2 + 0];
            float4 p1 = pan[d*2 + 1];
            const float* sr = srow + d*8;
            float zd = z[d];
            acc[ 0] = fmaf(p0.x, zd, acc[ 0]);
            acc[ 1] = fmaf(p0.y, zd, acc[ 1]);
            acc[ 2] = fmaf(p0.z, zd, acc[ 2]);
            acc[ 3] = fmaf(p0.w, zd, acc[ 3]);
            acc[ 4] = fmaf(p1.x, zd, acc[ 4]);
            acc[ 5] = fmaf(p1.y, zd, acc[ 5]);
            acc[ 6] = fmaf(p1.z, zd, acc[ 6]);
            acc[ 7] = fmaf(p1.w, zd, acc[ 7]);
            acc[ 8] = fmaf(sr[0], zd, acc[ 8]);
            acc[ 9] = fmaf(sr[1], zd, acc[ 9]);
            acc[10] = fmaf(sr[2], zd, acc[10]);
            acc[11] = fmaf(sr[3], zd, acc[11]);
            acc[12] = fmaf(sr[4], zd, acc[12]);
            acc[13] = fmaf(sr[5], zd, acc[13]);
            acc[14] = fmaf(sr[6], zd, acc[14]);
            acc[15] = fmaf(sr[7], zd, acc[15]);
        }
        const int kb = c*16;
        const float* nk = n1g + kb;
#pragma unroll
        for (int t = 0; t < 16; ++t) {
            float dist = (sum_rr - 2.0f*acc[t]) + nk[t];
            if (dist < best1) { best1 = dist; i1 = kb + t; }
        }
    }

    // ---- decode: out = T0[i0] + T1[i1] + b_out ----
    const float4* t0r = reinterpret_cast<const float4*>(T0 + (size_t)i0 * MEL_BINS);
    const float4* t1r = reinterpret_cast<const float4*>(T1 + (size_t)i1 * MEL_BINS);
    float4* outr = reinterpret_cast<float4*>(out_mel + (size_t)b * MEL_BINS);
#pragma unroll 4
    for (int q = 0; q < MEL_BINS / 4; ++q) {
        float4 a = t0r[q], cc = t1r[q];
        float4 o;
        o.x = a.x + cc.x + b_out[4*q + 0];
        o.y = a.y + cc.y + b_out[4*q + 1];
        o.z = a.z + cc.z + b_out[4*q + 2];
        o.w = a.w + cc.w + b_out[4*q + 3];
        outr[q] = o;
    }

    out_idx[2*(size_t)b + 0] = (float)i0;
    out_idx[2*(size_t)b + 1] = (float)i1;
}

extern "C" void kernel_launch(void* const* d_in, const int* in_sizes, int n_in,
                              void* d_out, int out_size, void* d_ws, size_t ws_size,
                              hipStream_t stream)
{
    const float* mel   = (const float*)d_in[0];
    const float* W_in  = (const float*)d_in[1];
    const float* b_in  = (const float*)d_in[2];
    const float* cb0   = (const float*)d_in[3];
    const float* cb1   = (const float*)d_in[4];
    const float* W_out = (const float*)d_in[5];
    const float* b_out = (const float*)d_in[6];

    float* ws      = (float*)d_ws;                 // 230400 bytes used
    float* out_mel = (float*)d_out;
    float* out_idx = (float*)d_out + (size_t)B_ROWS * MEL_BINS;

    rvq_precomp<<<(WS_TOT + 255) / 256, 256, 0, stream>>>(W_in, cb0, cb1, W_out, ws);
    rvq_main<<<B_ROWS / 256, 256, 0, stream>>>(mel, b_in, cb0, cb1, b_out, ws,
                                               out_mel, out_idx);
}